// Round 4
// baseline (167.464 us; speedup 1.0000x reference)
//
#include <hip/hip_runtime.h>

#define EDGE_BLOCKS  1024
#define EDGE_THREADS 512
#define PACK_WORDS_MAX 12512   // 50,048 B LDS table -> supports n_nodes <= 100,096

// ws layout (bytes):
//   [8192, 8192+4*n_words) : packed 4-bit node-class table
#define WS_PACK_OFF    8192

#define LOG2E 1.44269504088896f
#define LN2   0.69314718055995f

// Persistent device-global accumulator (graph-replay safe: last block resets).
__device__ double       g_acc = 0.0;
__device__ unsigned int g_cnt = 0u;

// ---------- kernel A: pack node classes to nibbles (once, 400KB -> 50KB) ----------
__global__ __launch_bounds__(256) void pack_classes(
    const int* __restrict__ node_classes,
    unsigned* __restrict__ packed,
    int n_nodes, int n_words)
{
    int w = blockIdx.x * blockDim.x + threadIdx.x;
    if (w >= n_words) return;

    int base = w << 3;
    unsigned v = 0;
    if (base + 8 <= n_nodes) {
        const int4* p = (const int4*)(node_classes + base);
        int4 c0 = p[0];
        int4 c1 = p[1];
        v  = ((unsigned)c0.x & 0xFu)
           | (((unsigned)c0.y & 0xFu) << 4)
           | (((unsigned)c0.z & 0xFu) << 8)
           | (((unsigned)c0.w & 0xFu) << 12)
           | (((unsigned)c1.x & 0xFu) << 16)
           | (((unsigned)c1.y & 0xFu) << 20)
           | (((unsigned)c1.z & 0xFu) << 24)
           | (((unsigned)c1.w & 0xFu) << 28);
    } else {
        #pragma unroll
        for (int j = 0; j < 8; ++j) {
            int n = base + j;
            unsigned c = (n < n_nodes) ? (unsigned)node_classes[n] : 0u;
            v |= (c & 0xFu) << (4 * j);
        }
    }
    packed[w] = v;
}

// 4-edge compute body (LDS nibble gather + masked BCE-with-logits terms)
#define COMPUTE4(si, di, sc)                                                  \
    do {                                                                      \
        unsigned wa0 = s_packed[(si).x >> 3], wa1 = s_packed[(si).y >> 3];    \
        unsigned wa2 = s_packed[(si).z >> 3], wa3 = s_packed[(si).w >> 3];    \
        unsigned wb0 = s_packed[(di).x >> 3], wb1 = s_packed[(di).y >> 3];    \
        unsigned wb2 = s_packed[(di).z >> 3], wb3 = s_packed[(di).w >> 3];    \
        int a0 = (wa0 >> (((si).x & 7) << 2)) & 0xF;                          \
        int a1 = (wa1 >> (((si).y & 7) << 2)) & 0xF;                          \
        int a2 = (wa2 >> (((si).z & 7) << 2)) & 0xF;                          \
        int a3 = (wa3 >> (((si).w & 7) << 2)) & 0xF;                          \
        int b0 = (wb0 >> (((di).x & 7) << 2)) & 0xF;                          \
        int b1 = (wb1 >> (((di).y & 7) << 2)) & 0xF;                          \
        int b2 = (wb2 >> (((di).z & 7) << 2)) & 0xF;                          \
        int b3 = (wb3 >> (((di).w & 7) << 2)) & 0xF;                          \
        unsigned y0 = (s_mask[a0] >> b0) & 1u;                                \
        unsigned y1 = (s_mask[a1] >> b1) & 1u;                                \
        unsigned y2 = (s_mask[a2] >> b2) & 1u;                                \
        unsigned y3 = (s_mask[a3] >> b3) & 1u;                                \
        float s0 = (sc).x, s1 = (sc).y, s2 = (sc).z, s3 = (sc).w;             \
        float t0 = __builtin_amdgcn_exp2f(-fabsf(s0) * LOG2E);                \
        float t1 = __builtin_amdgcn_exp2f(-fabsf(s1) * LOG2E);                \
        float t2 = __builtin_amdgcn_exp2f(-fabsf(s2) * LOG2E);                \
        float t3 = __builtin_amdgcn_exp2f(-fabsf(s3) * LOG2E);                \
        acc_a += fmaxf(s0, 0.0f) - (y0 ? s0 : 0.0f);                          \
        acc_a += fmaxf(s1, 0.0f) - (y1 ? s1 : 0.0f);                          \
        acc_a += fmaxf(s2, 0.0f) - (y2 ? s2 : 0.0f);                          \
        acc_a += fmaxf(s3, 0.0f) - (y3 ? s3 : 0.0f);                          \
        acc_l += __builtin_amdgcn_logf(1.0f + t0);                            \
        acc_l += __builtin_amdgcn_logf(1.0f + t1);                            \
        acc_l += __builtin_amdgcn_logf(1.0f + t2);                            \
        acc_l += __builtin_amdgcn_logf(1.0f + t3);                            \
    } while (0)

// ---------- kernel B: edge loss (8 edges/trip, depth-1 prefetch) + reduce ----
// 1024 blocks x 512 threads = 524K threads; 1M octs -> ~2 trips/thread.
// Depth-1 prefetch of the next oct means all ~12 16B loads are issued before
// the first compute needs them: one latency exposure per thread.
// __launch_bounds__(512,4): VGPR cap 128 (in-flight payload 48 + temps ~= 90,
// no spill expected); 16 waves/CU; LDS 2x50KB resident.
__global__ __launch_bounds__(EDGE_THREADS, 4) void edge_loss_lds(
    const unsigned* __restrict__ packed_g,
    const float* __restrict__ edge_scores,
    const int*   __restrict__ edge_src,
    const int*   __restrict__ edge_dst,
    const float* __restrict__ adj,
    float*       __restrict__ out,
    int n_edges, int n_words, float inv_n)
{
    __shared__ unsigned s_packed[PACK_WORDS_MAX]; // 50,048 B
    __shared__ unsigned s_mask[16];
    __shared__ float    s_wsum[EDGE_THREADS / 64];

    const int tid = threadIdx.x;

    if (tid < 16) {
        unsigned m = 0u;
        if (tid < 12) {
            #pragma unroll
            for (int j = 0; j < 12; ++j)
                if (adj[tid * 12 + j] > 0.5f) m |= (1u << j);
        }
        s_mask[tid] = m;
    }
    {
        // stage the 50KB packed table (L2-resident: 1024 blocks x 50KB = 51MB L2 reads)
        int nv = n_words >> 2;
        const uint4* p4 = (const uint4*)packed_g;
        for (int i = tid; i < nv; i += EDGE_THREADS) {
            uint4 v = p4[i];
            s_packed[4*i+0] = v.x; s_packed[4*i+1] = v.y;
            s_packed[4*i+2] = v.z; s_packed[4*i+3] = v.w;
        }
        for (int i = (nv << 2) + tid; i < n_words; i += EDGE_THREADS)
            s_packed[i] = packed_g[i];
    }
    __syncthreads();

    const int gtid   = blockIdx.x * EDGE_THREADS + tid;
    const int stride = gridDim.x * EDGE_THREADS;
    const int noct   = n_edges >> 3;

    const int4*   srcv = (const int4*)  edge_src;   // oct g -> [2g], [2g+1]
    const int4*   dstv = (const int4*)  edge_dst;
    const float4* scov = (const float4*)edge_scores;

    float acc_a = 0.0f;   // max(s,0) - y*s terms
    float acc_l = 0.0f;   // log-domain softplus terms (scale by LN2 at end)

    int g = gtid;
    if (g < noct) {
        // prefetch trip 0 (6 x 16B loads)
        int4   si0 = srcv[2*g],   si1 = srcv[2*g+1];
        int4   di0 = dstv[2*g],   di1 = dstv[2*g+1];
        float4 sc0 = scov[2*g],   sc1 = scov[2*g+1];

        while (true) {
            const int gn = g + stride;
            const bool more = (gn < noct);
            int4 si0n, si1n, di0n, di1n; float4 sc0n, sc1n;
            if (more) {          // issue next trip's 6 loads before compute
                si0n = srcv[2*gn];   si1n = srcv[2*gn+1];
                di0n = dstv[2*gn];   di1n = dstv[2*gn+1];
                sc0n = scov[2*gn];   sc1n = scov[2*gn+1];
            }

            COMPUTE4(si0, di0, sc0);
            COMPUTE4(si1, di1, sc1);

            if (!more) break;
            si0 = si0n; si1 = si1n;
            di0 = di0n; di1 = di1n;
            sc0 = sc0n; sc1 = sc1n;
            g = gn;
        }
    }

    // scalar tail (n_edges not divisible by 8)
    for (int e = (noct << 3) + gtid; e < n_edges; e += stride) {
        int n = edge_src[e], m = edge_dst[e];
        int a = (s_packed[n >> 3] >> ((n & 7) << 2)) & 0xF;
        int b = (s_packed[m >> 3] >> ((m & 7) << 2)) & 0xF;
        unsigned y = (s_mask[a] >> b) & 1u;
        float s = edge_scores[e];
        float t = __builtin_amdgcn_exp2f(-fabsf(s) * LOG2E);
        acc_a += fmaxf(s, 0.0f) - (y ? s : 0.0f);
        acc_l += __builtin_amdgcn_logf(1.0f + t);
    }

    float acc = fmaf(LN2, acc_l, acc_a);

    #pragma unroll
    for (int off = 32; off > 0; off >>= 1)
        acc += __shfl_down(acc, off, 64);

    const int wave = tid >> 6;
    const int lane = tid & 63;
    if (lane == 0) s_wsum[wave] = acc;
    __syncthreads();

    if (tid == 0) {
        double bsum = 0.0;
        #pragma unroll
        for (int w = 0; w < EDGE_THREADS / 64; ++w) bsum += (double)s_wsum[w];

        atomicAdd(&g_acc, bsum);
        __threadfence();
        unsigned old = atomicAdd(&g_cnt, 1u);
        if (old == gridDim.x - 1) {
            __threadfence();
            double total = g_acc;
            out[0] = (float)(total * (double)inv_n);
            g_acc = 0.0;          // restore clean state for next graph replay
            __threadfence();
            g_cnt = 0u;
        }
    }
}

// ---------- fallback: too many nodes for the LDS table ----------
__global__ __launch_bounds__(256) void edge_loss_fallback(
    const int*   __restrict__ node_classes,
    const float* __restrict__ edge_scores,
    const int*   __restrict__ edge_src,
    const int*   __restrict__ edge_dst,
    const float* __restrict__ adj,
    float*       __restrict__ out,
    int n_edges, float inv_n)
{
    __shared__ unsigned s_mask[16];
    const int tid = threadIdx.x;
    if (tid < 12) {
        unsigned m = 0u;
        for (int j = 0; j < 12; ++j)
            if (adj[tid * 12 + j] > 0.5f) m |= (1u << j);
        s_mask[tid] = m;
    }
    __syncthreads();
    const int gtid   = blockIdx.x * 256 + tid;
    const int stride = gridDim.x * 256;
    float acc = 0.0f;
    for (int e = gtid; e < n_edges; e += stride) {
        int a = node_classes[edge_src[e]];
        int b = node_classes[edge_dst[e]];
        float y = (float)((s_mask[a] >> b) & 1u);
        float s = edge_scores[e];
        float t = __builtin_amdgcn_exp2f(-fabsf(s) * LOG2E);
        acc += fmaxf(s, 0.0f) - s * y + LN2 * __builtin_amdgcn_logf(1.0f + t);
    }
    #pragma unroll
    for (int off = 32; off > 0; off >>= 1)
        acc += __shfl_down(acc, off, 64);
    __shared__ float s_wsum[4];
    const int wave = tid >> 6, lane = tid & 63;
    if (lane == 0) s_wsum[wave] = acc;
    __syncthreads();
    if (tid == 0) {
        double bsum = (double)s_wsum[0] + (double)s_wsum[1]
                    + (double)s_wsum[2] + (double)s_wsum[3];
        atomicAdd(&g_acc, bsum);
        __threadfence();
        unsigned old = atomicAdd(&g_cnt, 1u);
        if (old == gridDim.x - 1) {
            __threadfence();
            double total = g_acc;
            out[0] = (float)(total * (double)inv_n);
            g_acc = 0.0;
            __threadfence();
            g_cnt = 0u;
        }
    }
}

extern "C" void kernel_launch(void* const* d_in, const int* in_sizes, int n_in,
                              void* d_out, int out_size, void* d_ws, size_t ws_size,
                              hipStream_t stream) {
    const int*   node_classes = (const int*)  d_in[0];
    const float* edge_scores  = (const float*)d_in[1];
    const int*   edge_indices = (const int*)  d_in[2];
    const float* adj          = (const float*)d_in[3];

    const int n_nodes = in_sizes[0];
    const int n_edges = in_sizes[1];
    const int n_words = (n_nodes + 7) >> 3;

    const int* edge_src = edge_indices;
    const int* edge_dst = edge_indices + n_edges;

    char* ws = (char*)d_ws;
    unsigned* packed = (unsigned*)(ws + WS_PACK_OFF);
    float* out = (float*)d_out;
    const float inv_n = 1.0f / (float)n_edges;

    const size_t needed = (size_t)WS_PACK_OFF + (size_t)n_words * 4u;

    if (ws_size >= needed && n_words <= PACK_WORDS_MAX) {
        int pack_blocks = (n_words + 255) / 256;
        pack_classes<<<pack_blocks, 256, 0, stream>>>(
            node_classes, packed, n_nodes, n_words);
        edge_loss_lds<<<EDGE_BLOCKS, EDGE_THREADS, 0, stream>>>(
            packed, edge_scores, edge_src, edge_dst, adj, out,
            n_edges, n_words, inv_n);
    } else {
        edge_loss_fallback<<<2048, 256, 0, stream>>>(
            node_classes, edge_scores, edge_src, edge_dst, adj, out,
            n_edges, inv_n);
    }
}

// Round 6
// 135.700 us; speedup vs baseline: 1.2341x; 1.2341x over previous
//
#include <hip/hip_runtime.h>

#define EDGE_BLOCKS  512
#define EDGE_THREADS 1024
#define PACK_WORDS_MAX 12512   // 50,048 B LDS table -> supports n_nodes <= 100,096

// ws layout (bytes):
//   [8192, 8192+4*n_words) : packed 4-bit node-class table
#define WS_PACK_OFF    8192

#define LOG2E 1.44269504088896f
#define LN2   0.69314718055995f

// Persistent device-global accumulator (graph-replay safe: last block resets).
__device__ double       g_acc = 0.0;
__device__ unsigned int g_cnt = 0u;

// ---------- kernel A: pack node classes to nibbles (once, 400KB -> 50KB) ----------
__global__ __launch_bounds__(256) void pack_classes(
    const int* __restrict__ node_classes,
    unsigned* __restrict__ packed,
    int n_nodes, int n_words)
{
    int w = blockIdx.x * blockDim.x + threadIdx.x;
    if (w >= n_words) return;

    int base = w << 3;
    unsigned v = 0;
    if (base + 8 <= n_nodes) {
        const int4* p = (const int4*)(node_classes + base);
        int4 c0 = p[0];
        int4 c1 = p[1];
        v  = ((unsigned)c0.x & 0xFu)
           | (((unsigned)c0.y & 0xFu) << 4)
           | (((unsigned)c0.z & 0xFu) << 8)
           | (((unsigned)c0.w & 0xFu) << 12)
           | (((unsigned)c1.x & 0xFu) << 16)
           | (((unsigned)c1.y & 0xFu) << 20)
           | (((unsigned)c1.z & 0xFu) << 24)
           | (((unsigned)c1.w & 0xFu) << 28);
    } else {
        #pragma unroll
        for (int j = 0; j < 8; ++j) {
            int n = base + j;
            unsigned c = (n < n_nodes) ? (unsigned)node_classes[n] : 0u;
            v |= (c & 0xFu) << (4 * j);
        }
    }
    packed[w] = v;
}

// 4-edge compute body: accumulates into the two named float accumulators.
#define COMPUTE4(si, di, sc, aa, al)                                          \
    do {                                                                      \
        unsigned wa0 = s_packed[(si).x >> 3], wa1 = s_packed[(si).y >> 3];    \
        unsigned wa2 = s_packed[(si).z >> 3], wa3 = s_packed[(si).w >> 3];    \
        unsigned wb0 = s_packed[(di).x >> 3], wb1 = s_packed[(di).y >> 3];    \
        unsigned wb2 = s_packed[(di).z >> 3], wb3 = s_packed[(di).w >> 3];    \
        int a0 = (wa0 >> (((si).x & 7) << 2)) & 0xF;                          \
        int a1 = (wa1 >> (((si).y & 7) << 2)) & 0xF;                          \
        int a2 = (wa2 >> (((si).z & 7) << 2)) & 0xF;                          \
        int a3 = (wa3 >> (((si).w & 7) << 2)) & 0xF;                          \
        int b0 = (wb0 >> (((di).x & 7) << 2)) & 0xF;                          \
        int b1 = (wb1 >> (((di).y & 7) << 2)) & 0xF;                          \
        int b2 = (wb2 >> (((di).z & 7) << 2)) & 0xF;                          \
        int b3 = (wb3 >> (((di).w & 7) << 2)) & 0xF;                          \
        unsigned y0 = (s_mask[a0] >> b0) & 1u;                                \
        unsigned y1 = (s_mask[a1] >> b1) & 1u;                                \
        unsigned y2 = (s_mask[a2] >> b2) & 1u;                                \
        unsigned y3 = (s_mask[a3] >> b3) & 1u;                                \
        float s0 = (sc).x, s1 = (sc).y, s2 = (sc).z, s3 = (sc).w;             \
        float t0 = __builtin_amdgcn_exp2f(-fabsf(s0) * LOG2E);                \
        float t1 = __builtin_amdgcn_exp2f(-fabsf(s1) * LOG2E);                \
        float t2 = __builtin_amdgcn_exp2f(-fabsf(s2) * LOG2E);                \
        float t3 = __builtin_amdgcn_exp2f(-fabsf(s3) * LOG2E);                \
        aa += fmaxf(s0, 0.0f) - (y0 ? s0 : 0.0f);                            \
        aa += fmaxf(s1, 0.0f) - (y1 ? s1 : 0.0f);                            \
        aa += fmaxf(s2, 0.0f) - (y2 ? s2 : 0.0f);                            \
        aa += fmaxf(s3, 0.0f) - (y3 ? s3 : 0.0f);                            \
        al += __builtin_amdgcn_logf(1.0f + t0);                               \
        al += __builtin_amdgcn_logf(1.0f + t1);                               \
        al += __builtin_amdgcn_logf(1.0f + t2);                               \
        al += __builtin_amdgcn_logf(1.0f + t3);                               \
    } while (0)

// ---------- kernel B: edge loss, straight-line 4-group batch + reduce ----------
// 512 blocks x 1024 threads = 2 blocks/CU (LDS 2x50KB), 32 waves/CU = FULL
// wave occupancy; launch_bounds(1024,8) caps VGPR at 64.
// 2M 4-edge groups / 524,288 threads -> at most 4 groups per thread, handled
// by STRAIGHT-LINE code (no loop-carried prefetch for the compiler to
// de-pipeline): A,B loaded before LDS staging (latency hidden under staging),
// C,D loaded right after the barrier (latency hidden under A,B compute).
// Out-of-range groups use clamped indices + masked accumulation (no divergent
// loads). A grid-stride extension loop handles noct > 4*threads (empty here).
__global__ __launch_bounds__(EDGE_THREADS, 8) void edge_loss_lds(
    const unsigned* __restrict__ packed_g,
    const float* __restrict__ edge_scores,
    const int*   __restrict__ edge_src,
    const int*   __restrict__ edge_dst,
    const float* __restrict__ adj,
    float*       __restrict__ out,
    int n_edges, int n_words, float inv_n)
{
    __shared__ unsigned s_packed[PACK_WORDS_MAX]; // 50,048 B
    __shared__ unsigned s_mask[16];
    __shared__ float    s_wsum[EDGE_THREADS / 64];

    const int tid = threadIdx.x;

    if (tid < 16) {
        unsigned m = 0u;
        if (tid < 12) {
            #pragma unroll
            for (int j = 0; j < 12; ++j)
                if (adj[tid * 12 + j] > 0.5f) m |= (1u << j);
        }
        s_mask[tid] = m;
    }

    const int gtid = blockIdx.x * EDGE_THREADS + tid;
    const int S    = gridDim.x * EDGE_THREADS;   // 524,288 threads
    const int noct = n_edges >> 2;               // 4-edge groups

    const int4*   srcv = (const int4*)  edge_src;
    const int4*   dstv = (const int4*)  edge_dst;
    const float4* scov = (const float4*)edge_scores;

    const int  g0  = gtid;
    const bool inA = (g0 < noct);
    const bool mB  = (g0 +     S) < noct;
    const bool mC  = (g0 + 2 * S) < noct;
    const bool mD  = (g0 + 3 * S) < noct;
    const int  cB  = mB ? (g0 + S)     : g0;   // clamped: always a valid index
    const int  cC  = mC ? (g0 + 2 * S) : g0;
    const int  cD  = mD ? (g0 + 3 * S) : g0;

    // ---- issue A,B global loads BEFORE staging: latency hides under it ----
    int4 siA, diA, siB, diB; float4 scA, scB;
    if (inA) {
        siA = srcv[g0]; diA = dstv[g0]; scA = scov[g0];
        siB = srcv[cB]; diB = dstv[cB]; scB = scov[cB];
    }

    {
        // stage the 50KB packed table (L2-resident: 512 blocks x 50KB = 25MB)
        int nv = n_words >> 2;
        const uint4* p4 = (const uint4*)packed_g;
        for (int i = tid; i < nv; i += EDGE_THREADS) {
            uint4 v = p4[i];
            s_packed[4*i+0] = v.x; s_packed[4*i+1] = v.y;
            s_packed[4*i+2] = v.z; s_packed[4*i+3] = v.w;
        }
        for (int i = (nv << 2) + tid; i < n_words; i += EDGE_THREADS)
            s_packed[i] = packed_g[i];
    }
    __syncthreads();

    float acc_a = 0.0f;   // max(s,0) - y*s terms
    float acc_l = 0.0f;   // log-domain softplus terms (scale by LN2 at end)

    if (inA) {
        // ---- issue C,D loads now; their latency hides under A,B compute ----
        int4   siC = srcv[cC], diC = dstv[cC];
        int4   siD = srcv[cD], diD = dstv[cD];
        float4 scC = scov[cC], scD = scov[cD];

        COMPUTE4(siA, diA, scA, acc_a, acc_l);           // A always valid

        float aB = 0.0f, lB = 0.0f;
        COMPUTE4(siB, diB, scB, aB, lB);
        acc_a += mB ? aB : 0.0f;  acc_l += mB ? lB : 0.0f;

        float aC = 0.0f, lC = 0.0f;
        COMPUTE4(siC, diC, scC, aC, lC);
        acc_a += mC ? aC : 0.0f;  acc_l += mC ? lC : 0.0f;

        float aD = 0.0f, lD = 0.0f;
        COMPUTE4(siD, diD, scD, aD, lD);
        acc_a += mD ? aD : 0.0f;  acc_l += mD ? lD : 0.0f;
    }

    // generality: groups beyond 4 per thread (empty at this problem size)
    for (int g = g0 + 4 * S; g < noct; g += S) {
        int4 si = srcv[g], di = dstv[g]; float4 sc = scov[g];
        COMPUTE4(si, di, sc, acc_a, acc_l);
    }

    // scalar tail (n_edges not divisible by 4)
    for (int e = (noct << 2) + gtid; e < n_edges; e += S) {
        int n = edge_src[e], m = edge_dst[e];
        int a = (s_packed[n >> 3] >> ((n & 7) << 2)) & 0xF;
        int b = (s_packed[m >> 3] >> ((m & 7) << 2)) & 0xF;
        unsigned y = (s_mask[a] >> b) & 1u;
        float s = edge_scores[e];
        float t = __builtin_amdgcn_exp2f(-fabsf(s) * LOG2E);
        acc_a += fmaxf(s, 0.0f) - (y ? s : 0.0f);
        acc_l += __builtin_amdgcn_logf(1.0f + t);
    }

    float acc = fmaf(LN2, acc_l, acc_a);

    #pragma unroll
    for (int off = 32; off > 0; off >>= 1)
        acc += __shfl_down(acc, off, 64);

    const int wave = tid >> 6;
    const int lane = tid & 63;
    if (lane == 0) s_wsum[wave] = acc;
    __syncthreads();

    if (tid == 0) {
        double bsum = 0.0;
        #pragma unroll
        for (int w = 0; w < EDGE_THREADS / 64; ++w) bsum += (double)s_wsum[w];

        atomicAdd(&g_acc, bsum);
        __threadfence();
        unsigned old = atomicAdd(&g_cnt, 1u);
        if (old == gridDim.x - 1) {
            __threadfence();
            double total = g_acc;
            out[0] = (float)(total * (double)inv_n);
            g_acc = 0.0;          // restore clean state for next graph replay
            __threadfence();
            g_cnt = 0u;
        }
    }
}

// ---------- fallback: too many nodes for the LDS table ----------
__global__ __launch_bounds__(256) void edge_loss_fallback(
    const int*   __restrict__ node_classes,
    const float* __restrict__ edge_scores,
    const int*   __restrict__ edge_src,
    const int*   __restrict__ edge_dst,
    const float* __restrict__ adj,
    float*       __restrict__ out,
    int n_edges, float inv_n)
{
    __shared__ unsigned s_mask[16];
    const int tid = threadIdx.x;
    if (tid < 12) {
        unsigned m = 0u;
        for (int j = 0; j < 12; ++j)
            if (adj[tid * 12 + j] > 0.5f) m |= (1u << j);
        s_mask[tid] = m;
    }
    __syncthreads();
    const int gtid   = blockIdx.x * 256 + tid;
    const int stride = gridDim.x * 256;
    float acc = 0.0f;
    for (int e = gtid; e < n_edges; e += stride) {
        int a = node_classes[edge_src[e]];
        int b = node_classes[edge_dst[e]];
        float y = (float)((s_mask[a] >> b) & 1u);
        float s = edge_scores[e];
        float t = __builtin_amdgcn_exp2f(-fabsf(s) * LOG2E);
        acc += fmaxf(s, 0.0f) - s * y + LN2 * __builtin_amdgcn_logf(1.0f + t);
    }
    #pragma unroll
    for (int off = 32; off > 0; off >>= 1)
        acc += __shfl_down(acc, off, 64);
    __shared__ float s_wsum[4];
    const int wave = tid >> 6, lane = tid & 63;
    if (lane == 0) s_wsum[wave] = acc;
    __syncthreads();
    if (tid == 0) {
        double bsum = (double)s_wsum[0] + (double)s_wsum[1]
                    + (double)s_wsum[2] + (double)s_wsum[3];
        atomicAdd(&g_acc, bsum);
        __threadfence();
        unsigned old = atomicAdd(&g_cnt, 1u);
        if (old == gridDim.x - 1) {
            __threadfence();
            double total = g_acc;
            out[0] = (float)(total * (double)inv_n);
            g_acc = 0.0;
            __threadfence();
            g_cnt = 0u;
        }
    }
}

extern "C" void kernel_launch(void* const* d_in, const int* in_sizes, int n_in,
                              void* d_out, int out_size, void* d_ws, size_t ws_size,
                              hipStream_t stream) {
    const int*   node_classes = (const int*)  d_in[0];
    const float* edge_scores  = (const float*)d_in[1];
    const int*   edge_indices = (const int*)  d_in[2];
    const float* adj          = (const float*)d_in[3];

    const int n_nodes = in_sizes[0];
    const int n_edges = in_sizes[1];
    const int n_words = (n_nodes + 7) >> 3;

    const int* edge_src = edge_indices;
    const int* edge_dst = edge_indices + n_edges;

    char* ws = (char*)d_ws;
    unsigned* packed = (unsigned*)(ws + WS_PACK_OFF);
    float* out = (float*)d_out;
    const float inv_n = 1.0f / (float)n_edges;

    const size_t needed = (size_t)WS_PACK_OFF + (size_t)n_words * 4u;

    if (ws_size >= needed && n_words <= PACK_WORDS_MAX) {
        int pack_blocks = (n_words + 255) / 256;
        pack_classes<<<pack_blocks, 256, 0, stream>>>(
            node_classes, packed, n_nodes, n_words);
        edge_loss_lds<<<EDGE_BLOCKS, EDGE_THREADS, 0, stream>>>(
            packed, edge_scores, edge_src, edge_dst, adj, out,
            n_edges, n_words, inv_n);
    } else {
        edge_loss_fallback<<<2048, 256, 0, stream>>>(
            node_classes, edge_scores, edge_src, edge_dst, adj, out,
            n_edges, inv_n);
    }
}